// Round 3
// baseline (978.596 us; speedup 1.0000x reference)
//
#include <hip/hip_runtime.h>

typedef unsigned short u16;
typedef unsigned int u32;
typedef __attribute__((ext_vector_type(8))) __bf16 bf16x8;
typedef __attribute__((ext_vector_type(16))) float f32x16;

#define F32(x) ((float)(x))
// fixed-step dopri5, h = 1/3, tableau pre-multiplied by h
constexpr double HH = 1.0/3.0;
constexpr float HA10 = F32(HH*(1.0/5.0));
constexpr float HA20 = F32(HH*(3.0/40.0)),       HA21 = F32(HH*(9.0/40.0));
constexpr float HA30 = F32(HH*(44.0/45.0)),      HA31 = F32(HH*(-56.0/15.0)),     HA32 = F32(HH*(32.0/9.0));
constexpr float HA40 = F32(HH*(19372.0/6561.0)), HA41 = F32(HH*(-25360.0/2187.0)), HA42 = F32(HH*(64448.0/6561.0)), HA43 = F32(HH*(-212.0/729.0));
constexpr float HA50 = F32(HH*(9017.0/3168.0)),  HA51 = F32(HH*(-355.0/33.0)),    HA52 = F32(HH*(46732.0/5247.0)), HA53 = F32(HH*(49.0/176.0)), HA54 = F32(HH*(-5103.0/18656.0));
constexpr float HB50 = F32(HH*(35.0/384.0)), HB52 = F32(HH*(500.0/1113.0)), HB53 = F32(HH*(125.0/192.0)),
                HB54 = F32(HH*(-2187.0/6784.0)), HB55 = F32(HH*(11.0/84.0));

// ws layout (bytes) — weights only now
#define OFF_WF1   0
#define OFF_WF2   49152
#define OFF_WH1   92160
#define OFF_WH2   116736

__device__ __forceinline__ u16 f2bf(float f) {
  __bf16 h = (__bf16)f;
  return __builtin_bit_cast(u16, h);
}
__device__ __forceinline__ u32 pk2(float a, float b) {
  return (u32)f2bf(a) | ((u32)f2bf(b) << 16);
}
__device__ __forceinline__ float bfl(u32 u) { return __builtin_bit_cast(float, u << 16); }
__device__ __forceinline__ float bfh(u32 u) { return __builtin_bit_cast(float, u & 0xffff0000u); }
__device__ __forceinline__ float tanhf_(float x) {
  float e = __expf(2.0f * x);
  return 1.0f - 2.0f / (e + 1.0f);
}
// X2 u16 index: row stride 384 elems (48 granules of 8), granule ^= row&7
__device__ __forceinline__ int xi(int r, int c) {
  return r * 384 + (((c >> 3) ^ (r & 7)) << 3) + (c & 7);
}

// ---------------- setup: pack weights as MFMA A-operand frags (m = output col) ----
// A-frag 32x32x16: lane l holds A[m = tile*32 + (l&31)][k = kc*16 + (l>>5)*8 + e]
__global__ void setup_kernel(const float* __restrict__ L,
  const float* __restrict__ aw1, const float* __restrict__ ab1,
  const float* __restrict__ aw2, const float* __restrict__ ab2,
  const float* __restrict__ rw1, const float* __restrict__ rb1,
  const float* __restrict__ rw2, const float* __restrict__ rb2,
  const float* __restrict__ ow1, const float* __restrict__ ob1,
  const float* __restrict__ ow2, const float* __restrict__ ob2,
  u16* __restrict__ Wf1, u16* __restrict__ Wf2,
  u16* __restrict__ Wh1, u16* __restrict__ Wh2)
{
  const int gid = blockIdx.x * blockDim.x + threadIdx.x;
  const int gstr = gridDim.x * blockDim.x;
  for (int i = gid; i < 62976; i += gstr) {
    float v; u16* dst;
    if (i < 24576) {               // Wf1: [wt 0..7][kc 0..5]  K = z(64)|u(16)|1,0...(16)
      const int j = i, e = j & 7, l = (j >> 3) & 63, f = j >> 9;
      const int wt = f / 6, kc = f - wt * 6;
      const int n = wt * 32 + (l & 31);
      const int k = kc * 16 + (l >> 5) * 8 + e;
      if (k < 80)       v = (n < 128) ? aw1[n * 80 + k] : rw1[(n - 128) * 80 + k];
      else if (k == 80) v = (n < 128) ? ab1[n] : rb1[n - 128];
      else              v = 0.0f;
      dst = Wf1 + j;
    } else if (i < 46080) {        // Wf2: [lt 0..1][kc 0..20] K = z(64)|bias(16)|H(256)
      const int j = i - 24576, e = j & 7, l = (j >> 3) & 63, f = j >> 9;
      const int lt = f / 21, kc = f - lt * 21;
      const int m = lt * 32 + (l & 31);
      const int kk = kc * 16 + (l >> 5) * 8 + e;
      if (kk < 64) {               // A = -(L L^T)
        float s = 0.0f;
        for (int q2 = 0; q2 < 64; ++q2) s += L[m * 64 + q2] * L[kk * 64 + q2];
        v = -s;
      } else if (kk == 64) v = ab2[m] + rb2[m];
      else if (kk < 80)    v = 0.0f;
      else if (kk < 208)   v = aw2[m * 128 + (kk - 80)];
      else                 v = rw2[m * 128 + (kk - 208)];
      dst = Wf2 + j;
    } else if (i < 58368) {        // Wh1: [wt 0..3][kc 0..5]
      const int j = i - 46080, e = j & 7, l = (j >> 3) & 63, f = j >> 9;
      const int wt = f / 6, kc = f - wt * 6;
      const int n = wt * 32 + (l & 31);
      const int k = kc * 16 + (l >> 5) * 8 + e;
      if (k < 80)       v = ow1[n * 80 + k];
      else if (k == 80) v = ob1[n];
      else              v = 0.0f;
      dst = Wh1 + j;
    } else {                       // Wh2: [kc 0..8]  K = bias(16)|H(128), out pad 20->32
      const int j = i - 58368, e = j & 7, l = (j >> 3) & 63, kc = j >> 9;
      const int m = l & 31;
      const int koff = (l >> 5) * 8 + e;
      if (m >= 20)      v = 0.0f;
      else if (kc == 0) v = (koff == 0) ? ob2[m] : 0.0f;
      else              v = ow2[m * 128 + ((kc - 1) * 16 + koff)];
      dst = Wh2 + j;
    }
    *dst = f2bf(v);
  }
}

// ---------------- fused: 3 fixed dopri5 steps (FSAL) + output head ----------------
// One block = 32 rows. 4 waves: lt = w&1 (latent col half), kh = w>>1 (GEMM2 K-half
// AND dopri5 state j-half). Each wave owns 8 state elems per lane.
__global__ __launch_bounds__(256, 3) void fused_kernel(
    const float* __restrict__ zt, const float* __restrict__ ut,
    const u16* __restrict__ Wf1, const u16* __restrict__ Wf2,
    const u16* __restrict__ Wh1, const u16* __restrict__ Wh2,
    float* __restrict__ outz, float* __restrict__ outy)
{
  __shared__ __align__(16) u16 X2[32 * 384];          // [z(64)|u(16)|1(16)|H(256)]
  __shared__ __align__(16) float REDa[2][2][64][4];   // GEMM2 K-half exchange (q even)
  __shared__ __align__(16) float REDb[2][2][64][4];   // (q odd)
  const int tid = threadIdx.x, w = tid >> 6, l = tid & 63, lo = l & 31, hi = l >> 5;
  const int lt = w & 1, kh = w >> 1;
  const int R0 = blockIdx.x * 32;

  // ---- weight fragments ----
  bf16x8 wfa[6], wfb[6];
  #pragma unroll
  for (int kc = 0; kc < 6; ++kc) {
    wfa[kc] = *(const bf16x8*)(Wf1 + (((2 * w)     * 6 + kc) * 64 + l) * 8);
    wfb[kc] = *(const bf16x8*)(Wf1 + (((2 * w + 1) * 6 + kc) * 64 + l) * 8);
  }
  bf16x8 w2[11];
  #pragma unroll
  for (int i = 0; i < 11; ++i) {
    const int kc = kh ? (i < 10 ? 11 + i : 20) : i;
    w2[i] = *(const bf16x8*)(Wf2 + ((lt * 21 + kc) * 64 + l) * 8);
  }

  // ---- stage u + ones (cols 64..95) ----
  {
    const int r = tid >> 3, c0 = 64 + (tid & 7) * 4;
    float v0, v1, v2, v3;
    if (c0 < 80) {
      const float4 uv = *(const float4*)&ut[(size_t)(R0 + r) * 16 + (c0 - 64)];
      v0 = uv.x; v1 = uv.y; v2 = uv.z; v3 = uv.w;
    } else { v0 = (c0 == 80) ? 1.0f : 0.0f; v1 = v2 = v3 = 0.0f; }
    *(uint2*)&X2[xi(r, c0)] = make_uint2(pk2(v0, v1), pk2(v2, v3));
  }

  // ---- z state: each wave owns cols cb..cb+3, cb+8..cb+11 of its row ----
  const int cb = lt * 32 + kh * 16 + 4 * hi;
  float z8[8];
  {
    const float4 za = *(const float4*)&zt[(size_t)(R0 + lo) * 64 + cb];
    const float4 zb = *(const float4*)&zt[(size_t)(R0 + lo) * 64 + cb + 8];
    z8[0] = za.x; z8[1] = za.y; z8[2] = za.z; z8[3] = za.w;
    z8[4] = zb.x; z8[5] = zb.y; z8[6] = zb.z; z8[7] = zb.w;
    *(uint2*)&X2[xi(lo, cb)]     = make_uint2(pk2(za.x, za.y), pk2(za.z, za.w));
    *(uint2*)&X2[xi(lo, cb + 8)] = make_uint2(pk2(zb.x, zb.y), pk2(zb.z, zb.w));
  }

  float kp8[8];

  auto feval = [&]() {
    __syncthreads();                           // zi visible
    // GEMM1: K=96, two sequential 32-col hidden tiles (low reg pressure)
    #pragma unroll
    for (int t2 = 0; t2 < 2; ++t2) {
      f32x16 a{};
      #pragma unroll
      for (int kc = 0; kc < 6; ++kc) {
        const bf16x8 bf = *(const bf16x8*)&X2[xi(lo, kc * 16 + hi * 8)];
        a = __builtin_amdgcn_mfma_f32_32x32x16_bf16(t2 ? wfb[kc] : wfa[kc], bf, a, 0, 0, 0);
      }
      const int hc = 96 + (2 * w + t2) * 32 + 4 * hi;
      #pragma unroll
      for (int q = 0; q < 4; ++q) {
        const float e0 = tanhf_(a[4*q]),   e1 = tanhf_(a[4*q+1]);
        const float e2 = tanhf_(a[4*q+2]), e3 = tanhf_(a[4*q+3]);
        *(uint2*)&X2[xi(lo, hc + q * 8)] = make_uint2(pk2(e0, e1), pk2(e2, e3));
      }
    }
    __syncthreads();                           // H visible
    // GEMM2: K=336 split 11/10 across kh
    f32x16 p{};
    #pragma unroll
    for (int i = 0; i < 10; ++i) {
      const int kc = kh ? (11 + i) : i;
      const int col = (kc < 4) ? kc * 16 : 80 + (kc - 4) * 16;
      const bf16x8 bf = *(const bf16x8*)&X2[xi(lo, col + hi * 8)];
      p = __builtin_amdgcn_mfma_f32_32x32x16_bf16(w2[i], bf, p, 0, 0, 0);
    }
    if (kh == 0) {
      const bf16x8 bf = *(const bf16x8*)&X2[xi(lo, 176 + hi * 8)];
      p = __builtin_amdgcn_mfma_f32_32x32x16_bf16(w2[10], bf, p, 0, 0, 0);
    }
    // exchange: send the j-half I don't own, receive mine
    const int oh = 1 - kh;
    *(float4*)&REDa[lt][oh][l][0] = make_float4(p[8*oh],   p[8*oh+1], p[8*oh+2], p[8*oh+3]);
    *(float4*)&REDb[lt][oh][l][0] = make_float4(p[8*oh+4], p[8*oh+5], p[8*oh+6], p[8*oh+7]);
    __syncthreads();                           // RED visible + all X2 reads done
    const float4 ra = *(const float4*)&REDa[lt][kh][l][0];
    const float4 rb = *(const float4*)&REDb[lt][kh][l][0];
    kp8[0] = p[8*kh]   + ra.x; kp8[1] = p[8*kh+1] + ra.y;
    kp8[2] = p[8*kh+2] + ra.z; kp8[3] = p[8*kh+3] + ra.w;
    kp8[4] = p[8*kh+4] + rb.x; kp8[5] = p[8*kh+5] + rb.y;
    kp8[6] = p[8*kh+6] + rb.z; kp8[7] = p[8*kh+7] + rb.w;
  };

  auto psto = [&](u32* d) {
    d[0] = pk2(kp8[0], kp8[1]); d[1] = pk2(kp8[2], kp8[3]);
    d[2] = pk2(kp8[4], kp8[5]); d[3] = pk2(kp8[6], kp8[7]);
  };
  auto kadd = [&](const u32* s, float c, float* zi) {
    #pragma unroll
    for (int q = 0; q < 4; ++q) {
      zi[2*q]   += c * bfl(s[q]);
      zi[2*q+1] += c * bfh(s[q]);
    }
  };
  auto stzi = [&](const float* v) {
    *(uint2*)&X2[xi(lo, cb)]     = make_uint2(pk2(v[0], v[1]), pk2(v[2], v[3]));
    *(uint2*)&X2[xi(lo, cb + 8)] = make_uint2(pk2(v[4], v[5]), pk2(v[6], v[7]));
  };

  feval();                                      // k1 of step 1
  #pragma unroll 1
  for (int st = 0; st < 3; ++st) {
    float yac[8], zi[8];
    u32 ks0[4], ks1[4], ks2[4], ks3[4];
    #pragma unroll
    for (int i = 0; i < 8; ++i) { yac[i] = HB50 * kp8[i]; zi[i] = z8[i] + HA10 * kp8[i]; }
    psto(ks0); stzi(zi);
    feval();                                    // k2
    #pragma unroll
    for (int i = 0; i < 8; ++i) zi[i] = z8[i] + HA21 * kp8[i];
    kadd(ks0, HA20, zi); psto(ks1); stzi(zi);
    feval();                                    // k3
    #pragma unroll
    for (int i = 0; i < 8; ++i) { yac[i] += HB52 * kp8[i]; zi[i] = z8[i] + HA32 * kp8[i]; }
    kadd(ks0, HA30, zi); kadd(ks1, HA31, zi); psto(ks2); stzi(zi);
    feval();                                    // k4
    #pragma unroll
    for (int i = 0; i < 8; ++i) { yac[i] += HB53 * kp8[i]; zi[i] = z8[i] + HA43 * kp8[i]; }
    kadd(ks0, HA40, zi); kadd(ks1, HA41, zi); kadd(ks2, HA42, zi); psto(ks3); stzi(zi);
    feval();                                    // k5
    #pragma unroll
    for (int i = 0; i < 8; ++i) { yac[i] += HB54 * kp8[i]; zi[i] = z8[i] + HA54 * kp8[i]; }
    kadd(ks0, HA50, zi); kadd(ks1, HA51, zi); kadd(ks2, HA52, zi); kadd(ks3, HA53, zi); stzi(zi);
    feval();                                    // k6
    #pragma unroll
    for (int i = 0; i < 8; ++i) { yac[i] += HB55 * kp8[i]; z8[i] += yac[i]; }
    stzi(z8);                                   // y_new = next stage-1 input (FSAL)
    if (st < 2) feval();                        // k7 = k1 of next step
  }

  // ---- write zt1 (f32 from registers) ----
  *(float4*)&outz[(size_t)(R0 + lo) * 64 + cb]     = make_float4(z8[0], z8[1], z8[2], z8[3]);
  *(float4*)&outz[(size_t)(R0 + lo) * 64 + cb + 8] = make_float4(z8[4], z8[5], z8[6], z8[7]);

  // ---- output head (X2 z cols already hold bf16(z_final), u/ones intact) ----
  __syncthreads();
  bf16x8 h1f[6];
  #pragma unroll
  for (int kc = 0; kc < 6; ++kc)
    h1f[kc] = *(const bf16x8*)(Wh1 + ((w * 6 + kc) * 64 + l) * 8);
  f32x16 a{};
  #pragma unroll
  for (int kc = 0; kc < 6; ++kc) {
    const bf16x8 bf = *(const bf16x8*)&X2[xi(lo, kc * 16 + hi * 8)];
    a = __builtin_amdgcn_mfma_f32_32x32x16_bf16(h1f[kc], bf, a, 0, 0, 0);
  }
  {
    const int hc = 96 + w * 32 + 4 * hi;
    #pragma unroll
    for (int q = 0; q < 4; ++q) {
      const float e0 = fmaxf(a[4*q],   0.0f), e1 = fmaxf(a[4*q+1], 0.0f);
      const float e2 = fmaxf(a[4*q+2], 0.0f), e3 = fmaxf(a[4*q+3], 0.0f);
      *(uint2*)&X2[xi(lo, hc + q * 8)] = make_uint2(pk2(e0, e1), pk2(e2, e3));
    }
  }
  __syncthreads();
  if (w == 0) {
    bf16x8 h2f[9];
    #pragma unroll
    for (int kc = 0; kc < 9; ++kc)
      h2f[kc] = *(const bf16x8*)(Wh2 + (kc * 64 + l) * 8);
    f32x16 p{};
    #pragma unroll
    for (int kc = 0; kc < 9; ++kc) {
      const bf16x8 bf = *(const bf16x8*)&X2[xi(lo, 80 + kc * 16 + hi * 8)];
      p = __builtin_amdgcn_mfma_f32_32x32x16_bf16(h2f[kc], bf, p, 0, 0, 0);
    }
    #pragma unroll
    for (int q = 0; q < 3; ++q) {
      const int c = q * 8 + 4 * hi;
      if (c < 20) {
        *(float4*)&outy[(size_t)(R0 + lo) * 20 + c] =
            make_float4(p[4*q], p[4*q+1], p[4*q+2], p[4*q+3]);
      }
    }
  }
}

extern "C" void kernel_launch(void* const* d_in, const int* in_sizes, int n_in,
                              void* d_out, int out_size, void* d_ws, size_t ws_size,
                              hipStream_t stream) {
  const float* zt  = (const float*)d_in[0];
  const float* ut  = (const float*)d_in[2];
  const float* L   = (const float*)d_in[3];
  const float* aw1 = (const float*)d_in[4];
  const float* ab1 = (const float*)d_in[5];
  const float* aw2 = (const float*)d_in[6];
  const float* ab2 = (const float*)d_in[7];
  const float* rw1 = (const float*)d_in[8];
  const float* rb1 = (const float*)d_in[9];
  const float* rw2 = (const float*)d_in[10];
  const float* rb2 = (const float*)d_in[11];
  const float* ow1 = (const float*)d_in[12];
  const float* ob1 = (const float*)d_in[13];
  const float* ow2 = (const float*)d_in[14];
  const float* ob2 = (const float*)d_in[15];

  char* ws = (char*)d_ws;
  u16* Wf1 = (u16*)(ws + OFF_WF1);
  u16* Wf2 = (u16*)(ws + OFF_WF2);
  u16* Wh1 = (u16*)(ws + OFF_WH1);
  u16* Wh2 = (u16*)(ws + OFF_WH2);
  float* outz = (float*)d_out;
  float* outy = outz + (size_t)131072 * 64;

  hipLaunchKernelGGL(setup_kernel, dim3(64), dim3(256), 0, stream,
      L, aw1, ab1, aw2, ab2, rw1, rb1, rw2, rb2, ow1, ob1, ow2, ob2,
      Wf1, Wf2, Wh1, Wh2);
  hipLaunchKernelGGL(fused_kernel, dim3(4096), dim3(256), 0, stream,
      zt, ut, Wf1, Wf2, Wh1, Wh2, outz, outy);
}

// Round 4
// 279.845 us; speedup vs baseline: 3.4969x; 3.4969x over previous
//
#include <hip/hip_runtime.h>

typedef unsigned short u16;
typedef unsigned int u32;
typedef __attribute__((ext_vector_type(8))) __bf16 bf16x8;
typedef __attribute__((ext_vector_type(16))) float f32x16;

#define F32(x) ((float)(x))
// dopri5, single fixed step h = 1 (B5[6] == 0 and no error estimate -> 6 stages)
constexpr float A10 = F32(1.0/5.0);
constexpr float A20 = F32(3.0/40.0),       A21 = F32(9.0/40.0);
constexpr float A30 = F32(44.0/45.0),      A31 = F32(-56.0/15.0),     A32 = F32(32.0/9.0);
constexpr float A40 = F32(19372.0/6561.0), A41 = F32(-25360.0/2187.0), A42 = F32(64448.0/6561.0), A43 = F32(-212.0/729.0);
constexpr float A50 = F32(9017.0/3168.0),  A51 = F32(-355.0/33.0),    A52 = F32(46732.0/5247.0), A53 = F32(49.0/176.0), A54 = F32(-5103.0/18656.0);
constexpr float B50 = F32(35.0/384.0), B52 = F32(500.0/1113.0), B53 = F32(125.0/192.0),
                B54 = F32(-2187.0/6784.0), B55 = F32(11.0/84.0);

// ws layout (bytes) — weights only
#define OFF_WF1   0
#define OFF_WF2   49152
#define OFF_WH1   92160
#define OFF_WH2   116736

__device__ __forceinline__ u16 f2bf(float f) {
  __bf16 h = (__bf16)f;
  return __builtin_bit_cast(u16, h);
}
__device__ __forceinline__ u32 pk2(float a, float b) {
  return (u32)f2bf(a) | ((u32)f2bf(b) << 16);
}
__device__ __forceinline__ float bfl(u32 u) { return __builtin_bit_cast(float, u << 16); }
__device__ __forceinline__ float bfh(u32 u) { return __builtin_bit_cast(float, u & 0xffff0000u); }
__device__ __forceinline__ float tanhf_(float x) {
  float e = __expf(2.0f * x);
  return 1.0f - 2.0f / (e + 1.0f);
}
// X2 u16 index: row stride 384 elems (48 granules of 8), granule ^= row&7
__device__ __forceinline__ int xi(int r, int c) {
  return r * 384 + (((c >> 3) ^ (r & 7)) << 3) + (c & 7);
}

// ---------------- setup: pack weights as MFMA A-operand frags (m = output col) ----
// A-frag 32x32x16: lane l holds A[m = tile*32 + (l&31)][k = kc*16 + (l>>5)*8 + e]
__global__ void setup_kernel(const float* __restrict__ L,
  const float* __restrict__ aw1, const float* __restrict__ ab1,
  const float* __restrict__ aw2, const float* __restrict__ ab2,
  const float* __restrict__ rw1, const float* __restrict__ rb1,
  const float* __restrict__ rw2, const float* __restrict__ rb2,
  const float* __restrict__ ow1, const float* __restrict__ ob1,
  const float* __restrict__ ow2, const float* __restrict__ ob2,
  u16* __restrict__ Wf1, u16* __restrict__ Wf2,
  u16* __restrict__ Wh1, u16* __restrict__ Wh2)
{
  const int gid = blockIdx.x * blockDim.x + threadIdx.x;
  const int gstr = gridDim.x * blockDim.x;
  for (int i = gid; i < 62976; i += gstr) {
    float v; u16* dst;
    if (i < 24576) {               // Wf1: [wt 0..7][kc 0..5]  K = z(64)|u(16)|1,0...(16)
      const int j = i, e = j & 7, l = (j >> 3) & 63, f = j >> 9;
      const int wt = f / 6, kc = f - wt * 6;
      const int n = wt * 32 + (l & 31);
      const int k = kc * 16 + (l >> 5) * 8 + e;
      if (k < 80)       v = (n < 128) ? aw1[n * 80 + k] : rw1[(n - 128) * 80 + k];
      else if (k == 80) v = (n < 128) ? ab1[n] : rb1[n - 128];
      else              v = 0.0f;
      dst = Wf1 + j;
    } else if (i < 46080) {        // Wf2: [lt 0..1][kc 0..20] K = z(64)|bias(16)|H(256)
      const int j = i - 24576, e = j & 7, l = (j >> 3) & 63, f = j >> 9;
      const int lt = f / 21, kc = f - lt * 21;
      const int m = lt * 32 + (l & 31);
      const int kk = kc * 16 + (l >> 5) * 8 + e;
      if (kk < 64) {               // A = -(L L^T)
        float s = 0.0f;
        for (int q2 = 0; q2 < 64; ++q2) s += L[m * 64 + q2] * L[kk * 64 + q2];
        v = -s;
      } else if (kk == 64) v = ab2[m] + rb2[m];
      else if (kk < 80)    v = 0.0f;
      else if (kk < 208)   v = aw2[m * 128 + (kk - 80)];
      else                 v = rw2[m * 128 + (kk - 208)];
      dst = Wf2 + j;
    } else if (i < 58368) {        // Wh1: [wt 0..3][kc 0..5]
      const int j = i - 46080, e = j & 7, l = (j >> 3) & 63, f = j >> 9;
      const int wt = f / 6, kc = f - wt * 6;
      const int n = wt * 32 + (l & 31);
      const int k = kc * 16 + (l >> 5) * 8 + e;
      if (k < 80)       v = ow1[n * 80 + k];
      else if (k == 80) v = ob1[n];
      else              v = 0.0f;
      dst = Wh1 + j;
    } else {                       // Wh2: [kc 0..8]  K = bias(16)|H(128), out pad 20->32
      const int j = i - 58368, e = j & 7, l = (j >> 3) & 63, kc = j >> 9;
      const int m = l & 31;
      const int koff = (l >> 5) * 8 + e;
      if (m >= 20)      v = 0.0f;
      else if (kc == 0) v = (koff == 0) ? ob2[m] : 0.0f;
      else              v = ow2[m * 128 + ((kc - 1) * 16 + koff)];
      dst = Wh2 + j;
    }
    *dst = f2bf(v);
  }
}

// ---------------- fused: ONE fixed dopri5 step (6 stages) + output head ----------------
// One block = 32 rows. 4 waves: lt = w&1 (latent col half), kh = w>>1 (GEMM2 K-half
// AND dopri5 state quarter). Each wave owns 8 state elems per lane.
__global__ __launch_bounds__(256) __attribute__((amdgpu_waves_per_eu(3, 3)))
void fused_kernel(
    const float* __restrict__ zt, const float* __restrict__ ut,
    const u16* __restrict__ Wf1, const u16* __restrict__ Wf2,
    const u16* __restrict__ Wh1, const u16* __restrict__ Wh2,
    float* __restrict__ outz, float* __restrict__ outy)
{
  __shared__ __align__(16) u16 X2[32 * 384];          // [z(64)|u(16)|1(16)|H(256)]
  __shared__ __align__(16) u16 KS[4 * 32 * 68];       // k1..k4 bf16, thread-private slots
  __shared__ __align__(16) float REDa[2][2][64][4];   // GEMM2 K-half exchange
  __shared__ __align__(16) float REDb[2][2][64][4];
  const int tid = threadIdx.x, w = tid >> 6, l = tid & 63, lo = l & 31, hi = l >> 5;
  const int lt = w & 1, kh = w >> 1;
  const int R0 = blockIdx.x * 32;

  // ---- weight fragments ----
  bf16x8 wfa[6], wfb[6];
  #pragma unroll
  for (int kc = 0; kc < 6; ++kc) {
    wfa[kc] = *(const bf16x8*)(Wf1 + (((2 * w)     * 6 + kc) * 64 + l) * 8);
    wfb[kc] = *(const bf16x8*)(Wf1 + (((2 * w + 1) * 6 + kc) * 64 + l) * 8);
  }
  bf16x8 w2[11];
  #pragma unroll
  for (int i = 0; i < 11; ++i) {
    const int kc = kh ? (i < 10 ? 11 + i : 20) : i;
    w2[i] = *(const bf16x8*)(Wf2 + ((lt * 21 + kc) * 64 + l) * 8);
  }

  // ---- stage u + ones (cols 64..95) ----
  {
    const int r = tid >> 3, c0 = 64 + (tid & 7) * 4;
    float v0, v1, v2, v3;
    if (c0 < 80) {
      const float4 uv = *(const float4*)&ut[(size_t)(R0 + r) * 16 + (c0 - 64)];
      v0 = uv.x; v1 = uv.y; v2 = uv.z; v3 = uv.w;
    } else { v0 = (c0 == 80) ? 1.0f : 0.0f; v1 = v2 = v3 = 0.0f; }
    *(uint2*)&X2[xi(r, c0)] = make_uint2(pk2(v0, v1), pk2(v2, v3));
  }

  // ---- z state: each wave owns cols cb..cb+3, cb+8..cb+11 of row lo ----
  const int cb = lt * 32 + kh * 16 + 4 * hi;
  float z8[8];
  {
    const float4 za = *(const float4*)&zt[(size_t)(R0 + lo) * 64 + cb];
    const float4 zb = *(const float4*)&zt[(size_t)(R0 + lo) * 64 + cb + 8];
    z8[0] = za.x; z8[1] = za.y; z8[2] = za.z; z8[3] = za.w;
    z8[4] = zb.x; z8[5] = zb.y; z8[6] = zb.z; z8[7] = zb.w;
    *(uint2*)&X2[xi(lo, cb)]     = make_uint2(pk2(za.x, za.y), pk2(za.z, za.w));
    *(uint2*)&X2[xi(lo, cb + 8)] = make_uint2(pk2(zb.x, zb.y), pk2(zb.z, zb.w));
  }

  float kp8[8];

  auto feval = [&]() {
    __syncthreads();                           // zi visible
    // GEMM1: K=96, two sequential 32-col hidden tiles
    #pragma unroll
    for (int t2 = 0; t2 < 2; ++t2) {
      f32x16 a{};
      #pragma unroll
      for (int kc = 0; kc < 6; ++kc) {
        const bf16x8 bf = *(const bf16x8*)&X2[xi(lo, kc * 16 + hi * 8)];
        a = __builtin_amdgcn_mfma_f32_32x32x16_bf16(t2 ? wfb[kc] : wfa[kc], bf, a, 0, 0, 0);
      }
      const int hc = 96 + (2 * w + t2) * 32 + 4 * hi;
      #pragma unroll
      for (int q = 0; q < 4; ++q) {
        const float e0 = tanhf_(a[4*q]),   e1 = tanhf_(a[4*q+1]);
        const float e2 = tanhf_(a[4*q+2]), e3 = tanhf_(a[4*q+3]);
        *(uint2*)&X2[xi(lo, hc + q * 8)] = make_uint2(pk2(e0, e1), pk2(e2, e3));
      }
    }
    __syncthreads();                           // H visible
    // GEMM2: K=336 split 11/10 across kh
    f32x16 p{};
    #pragma unroll
    for (int i = 0; i < 10; ++i) {
      const int kc = kh ? (11 + i) : i;
      const int col = (kc < 4) ? kc * 16 : 80 + (kc - 4) * 16;
      const bf16x8 bf = *(const bf16x8*)&X2[xi(lo, col + hi * 8)];
      p = __builtin_amdgcn_mfma_f32_32x32x16_bf16(w2[i], bf, p, 0, 0, 0);
    }
    if (kh == 0) {
      const bf16x8 bf = *(const bf16x8*)&X2[xi(lo, 176 + hi * 8)];
      p = __builtin_amdgcn_mfma_f32_32x32x16_bf16(w2[10], bf, p, 0, 0, 0);
    }
    // exchange: send the half I don't own, receive mine
    const int oh = 1 - kh;
    *(float4*)&REDa[lt][oh][l][0] = make_float4(p[8*oh],   p[8*oh+1], p[8*oh+2], p[8*oh+3]);
    *(float4*)&REDb[lt][oh][l][0] = make_float4(p[8*oh+4], p[8*oh+5], p[8*oh+6], p[8*oh+7]);
    __syncthreads();                           // RED visible + all X2 reads done
    const float4 ra = *(const float4*)&REDa[lt][kh][l][0];
    const float4 rb = *(const float4*)&REDb[lt][kh][l][0];
    kp8[0] = p[8*kh]   + ra.x; kp8[1] = p[8*kh+1] + ra.y;
    kp8[2] = p[8*kh+2] + ra.z; kp8[3] = p[8*kh+3] + ra.w;
    kp8[4] = p[8*kh+4] + rb.x; kp8[5] = p[8*kh+5] + rb.y;
    kp8[6] = p[8*kh+6] + rb.z; kp8[7] = p[8*kh+7] + rb.w;
  };

  // k history in LDS (thread-private slots; no barrier needed)
  auto stks = [&](int slot) {
    u16* d = &KS[(slot * 32 + lo) * 68 + cb];
    *(uint2*)d       = make_uint2(pk2(kp8[0], kp8[1]), pk2(kp8[2], kp8[3]));
    *(uint2*)(d + 8) = make_uint2(pk2(kp8[4], kp8[5]), pk2(kp8[6], kp8[7]));
  };
  auto kadd = [&](int slot, float c, float* zi) {
    const u16* s = &KS[(slot * 32 + lo) * 68 + cb];
    const uint2 va = *(const uint2*)s;
    const uint2 vb = *(const uint2*)(s + 8);
    zi[0] += c * bfl(va.x); zi[1] += c * bfh(va.x);
    zi[2] += c * bfl(va.y); zi[3] += c * bfh(va.y);
    zi[4] += c * bfl(vb.x); zi[5] += c * bfh(vb.x);
    zi[6] += c * bfl(vb.y); zi[7] += c * bfh(vb.y);
  };
  auto stzi = [&](const float* v) {
    *(uint2*)&X2[xi(lo, cb)]     = make_uint2(pk2(v[0], v[1]), pk2(v[2], v[3]));
    *(uint2*)&X2[xi(lo, cb + 8)] = make_uint2(pk2(v[4], v[5]), pk2(v[6], v[7]));
  };

  float yac[8], zi[8];
  feval();                                      // k1
  #pragma unroll
  for (int i = 0; i < 8; ++i) { yac[i] = B50 * kp8[i]; zi[i] = z8[i] + A10 * kp8[i]; }
  stks(0); stzi(zi);
  feval();                                      // k2
  #pragma unroll
  for (int i = 0; i < 8; ++i) zi[i] = z8[i] + A21 * kp8[i];
  kadd(0, A20, zi); stks(1); stzi(zi);
  feval();                                      // k3
  #pragma unroll
  for (int i = 0; i < 8; ++i) { yac[i] += B52 * kp8[i]; zi[i] = z8[i] + A32 * kp8[i]; }
  kadd(0, A30, zi); kadd(1, A31, zi); stks(2); stzi(zi);
  feval();                                      // k4
  #pragma unroll
  for (int i = 0; i < 8; ++i) { yac[i] += B53 * kp8[i]; zi[i] = z8[i] + A43 * kp8[i]; }
  kadd(0, A40, zi); kadd(1, A41, zi); kadd(2, A42, zi); stks(3); stzi(zi);
  feval();                                      // k5
  #pragma unroll
  for (int i = 0; i < 8; ++i) { yac[i] += B54 * kp8[i]; zi[i] = z8[i] + A54 * kp8[i]; }
  kadd(0, A50, zi); kadd(1, A51, zi); kadd(2, A52, zi); kadd(3, A53, zi); stzi(zi);
  feval();                                      // k6
  #pragma unroll
  for (int i = 0; i < 8; ++i) { yac[i] += B55 * kp8[i]; z8[i] += yac[i]; }
  stzi(z8);                                     // final z -> X2 for the head

  // ---- write zt1 (f32 from registers) ----
  *(float4*)&outz[(size_t)(R0 + lo) * 64 + cb]     = make_float4(z8[0], z8[1], z8[2], z8[3]);
  *(float4*)&outz[(size_t)(R0 + lo) * 64 + cb + 8] = make_float4(z8[4], z8[5], z8[6], z8[7]);

  // ---- output head (X2 z cols hold bf16(z_final); u/ones intact) ----
  __syncthreads();
  bf16x8 h1f[6];
  #pragma unroll
  for (int kc = 0; kc < 6; ++kc)
    h1f[kc] = *(const bf16x8*)(Wh1 + ((w * 6 + kc) * 64 + l) * 8);
  f32x16 a{};
  #pragma unroll
  for (int kc = 0; kc < 6; ++kc) {
    const bf16x8 bf = *(const bf16x8*)&X2[xi(lo, kc * 16 + hi * 8)];
    a = __builtin_amdgcn_mfma_f32_32x32x16_bf16(h1f[kc], bf, a, 0, 0, 0);
  }
  {
    const int hc = 96 + w * 32 + 4 * hi;
    #pragma unroll
    for (int q = 0; q < 4; ++q) {
      const float e0 = fmaxf(a[4*q],   0.0f), e1 = fmaxf(a[4*q+1], 0.0f);
      const float e2 = fmaxf(a[4*q+2], 0.0f), e3 = fmaxf(a[4*q+3], 0.0f);
      *(uint2*)&X2[xi(lo, hc + q * 8)] = make_uint2(pk2(e0, e1), pk2(e2, e3));
    }
  }
  __syncthreads();
  if (w == 0) {
    bf16x8 h2f[9];
    #pragma unroll
    for (int kc = 0; kc < 9; ++kc)
      h2f[kc] = *(const bf16x8*)(Wh2 + (kc * 64 + l) * 8);
    f32x16 p{};
    #pragma unroll
    for (int kc = 0; kc < 9; ++kc) {
      const bf16x8 bf = *(const bf16x8*)&X2[xi(lo, 80 + kc * 16 + hi * 8)];
      p = __builtin_amdgcn_mfma_f32_32x32x16_bf16(h2f[kc], bf, p, 0, 0, 0);
    }
    #pragma unroll
    for (int q = 0; q < 3; ++q) {
      const int c = q * 8 + 4 * hi;
      if (c < 20) {
        *(float4*)&outy[(size_t)(R0 + lo) * 20 + c] =
            make_float4(p[4*q], p[4*q+1], p[4*q+2], p[4*q+3]);
      }
    }
  }
}

extern "C" void kernel_launch(void* const* d_in, const int* in_sizes, int n_in,
                              void* d_out, int out_size, void* d_ws, size_t ws_size,
                              hipStream_t stream) {
  const float* zt  = (const float*)d_in[0];
  const float* ut  = (const float*)d_in[2];
  const float* L   = (const float*)d_in[3];
  const float* aw1 = (const float*)d_in[4];
  const float* ab1 = (const float*)d_in[5];
  const float* aw2 = (const float*)d_in[6];
  const float* ab2 = (const float*)d_in[7];
  const float* rw1 = (const float*)d_in[8];
  const float* rb1 = (const float*)d_in[9];
  const float* rw2 = (const float*)d_in[10];
  const float* rb2 = (const float*)d_in[11];
  const float* ow1 = (const float*)d_in[12];
  const float* ob1 = (const float*)d_in[13];
  const float* ow2 = (const float*)d_in[14];
  const float* ob2 = (const float*)d_in[15];

  char* ws = (char*)d_ws;
  u16* Wf1 = (u16*)(ws + OFF_WF1);
  u16* Wf2 = (u16*)(ws + OFF_WF2);
  u16* Wh1 = (u16*)(ws + OFF_WH1);
  u16* Wh2 = (u16*)(ws + OFF_WH2);
  float* outz = (float*)d_out;
  float* outy = outz + (size_t)131072 * 64;

  hipLaunchKernelGGL(setup_kernel, dim3(64), dim3(256), 0, stream,
      L, aw1, ab1, aw2, ab2, rw1, rb1, rw2, rb2, ow1, ob1, ow2, ob2,
      Wf1, Wf2, Wh1, Wh2);
  hipLaunchKernelGGL(fused_kernel, dim3(4096), dim3(256), 0, stream,
      zt, ut, Wf1, Wf2, Wh1, Wh2, outz, outy);
}

// Round 5
// 174.792 us; speedup vs baseline: 5.5986x; 1.6010x over previous
//
#include <hip/hip_runtime.h>

typedef unsigned short u16;
typedef unsigned int u32;
typedef __attribute__((ext_vector_type(8))) __bf16 bf16x8;
typedef __attribute__((ext_vector_type(4))) float f32x4;

#define F32(x) ((float)(x))
// dopri5, single fixed step h = 1 (B5[6]==0, no error estimate -> 6 stages)
constexpr float A10 = F32(1.0/5.0);
constexpr float A20 = F32(3.0/40.0),       A21 = F32(9.0/40.0);
constexpr float A30 = F32(44.0/45.0),      A31 = F32(-56.0/15.0),     A32 = F32(32.0/9.0);
constexpr float A40 = F32(19372.0/6561.0), A41 = F32(-25360.0/2187.0), A42 = F32(64448.0/6561.0), A43 = F32(-212.0/729.0);
constexpr float A50 = F32(9017.0/3168.0),  A51 = F32(-355.0/33.0),    A52 = F32(46732.0/5247.0), A53 = F32(49.0/176.0), A54 = F32(-5103.0/18656.0);
constexpr float B50 = F32(35.0/384.0), B52 = F32(500.0/1113.0), B53 = F32(125.0/192.0),
                B54 = F32(-2187.0/6784.0), B55 = F32(11.0/84.0);

// weight regions, u16 units
#define OFF_WG1   0        // [16 ct][2 kc]  GEMM1 z-part      (16384)
#define OFF_WG2   16384    // [4 ct][10 kc]  GEMM2 z|H         (20480)
#define OFF_W1U   36864    // [16 ct]        GEMM1 u-part pad32 (8192)
#define OFF_WH1   45056    // [8 ct][2 kc]   head L1 z-part     (8192)
#define OFF_WH1U  53248    // [8 ct]         head L1 u-part     (4096)
#define OFF_WH2   57344    // [2 ot][4 kc]   head L2            (4096)
#define W_TOTAL   61440

__device__ __forceinline__ u16 f2bf(float f) {
  __bf16 h = (__bf16)f;
  return __builtin_bit_cast(u16, h);
}
__device__ __forceinline__ u32 pk2(float a, float b) {
  return (u32)f2bf(a) | ((u32)f2bf(b) << 16);
}
__device__ __forceinline__ float bfl(u32 u) { return __builtin_bit_cast(float, u << 16); }
__device__ __forceinline__ float bfh(u32 u) { return __builtin_bit_cast(float, u & 0xffff0000u); }
__device__ __forceinline__ float tanhf_(float x) {
  float e = __expf(2.0f * x);
  return 1.0f - 2.0f / (e + 1.0f);
}
// X2 [32 r][320 c] bf16, granule-XOR swizzle
__device__ __forceinline__ int xi(int r, int c) {
  return r * 320 + (((c >> 3) ^ (r & 7)) << 3) + (c & 7);
}
// C1 [32 r][256 c]
__device__ __forceinline__ int xiC(int r, int c) {
  return r * 256 + (((c >> 3) ^ (r & 7)) << 3) + (c & 7);
}

// ---------------- setup: pack weights as 16x16x32 A-frags --------------------
// A-frag: lane l holds A[m = base + (l&15)][k = kc*32 + (l>>4)*8 + e]
__global__ void setup_kernel(const float* __restrict__ L,
  const float* __restrict__ aw1, const float* __restrict__ rw1,
  const float* __restrict__ aw2, const float* __restrict__ rw2,
  const float* __restrict__ ow1, const float* __restrict__ ow2,
  u16* __restrict__ W)
{
  const int gid = blockIdx.x * blockDim.x + threadIdx.x;
  const int gstr = gridDim.x * blockDim.x;
  for (int i = gid; i < W_TOTAL; i += gstr) {
    float v;
    if (i < 16384) {                 // Wg1: hidden 256 x K=64 (z)
      const int j = i, e = j & 7, l = (j >> 3) & 63, f = j >> 9;
      const int ct = f >> 1, kc = f & 1;
      const int m = ct * 16 + (l & 15);
      const int k = kc * 32 + ((l >> 4) << 3) + e;
      v = (m < 128) ? aw1[m * 80 + k] : rw1[(m - 128) * 80 + k];
    } else if (i < 36864) {          // Wg2: lat 64 x K=320 (z:A | H:w2)
      const int j = i - 16384, e = j & 7, l = (j >> 3) & 63, f = j >> 9;
      const int ct = f / 10, kc = f - ct * 10;
      const int m = ct * 16 + (l & 15);
      const int kk = kc * 32 + ((l >> 4) << 3) + e;
      if (kk < 64) {                 // A = -(L L^T)
        float s = 0.0f;
        for (int q = 0; q < 64; ++q) s += L[m * 64 + q] * L[kk * 64 + q];
        v = -s;
      } else if (kk < 192) v = aw2[m * 128 + (kk - 64)];
      else                 v = rw2[m * 128 + (kk - 192)];
    } else if (i < 45056) {          // W1u: hidden 256 x K=32 (u pad)
      const int j = i - 36864, e = j & 7, l = (j >> 3) & 63, ct = j >> 9;
      const int m = ct * 16 + (l & 15);
      const int k = ((l >> 4) << 3) + e;
      v = (k < 16) ? ((m < 128) ? aw1[m * 80 + 64 + k] : rw1[(m - 128) * 80 + 64 + k]) : 0.0f;
    } else if (i < 53248) {          // Wh1: head hidden 128 x K=64 (z)
      const int j = i - 45056, e = j & 7, l = (j >> 3) & 63, f = j >> 9;
      const int ct = f >> 1, kc = f & 1;
      const int m = ct * 16 + (l & 15);
      const int k = kc * 32 + ((l >> 4) << 3) + e;
      v = ow1[m * 80 + k];
    } else if (i < 57344) {          // Wh1u: head hidden 128 x K=32 (u pad)
      const int j = i - 53248, e = j & 7, l = (j >> 3) & 63, ct = j >> 9;
      const int m = ct * 16 + (l & 15);
      const int k = ((l >> 4) << 3) + e;
      v = (k < 16) ? ow1[m * 80 + 64 + k] : 0.0f;
    } else {                         // Wh2: out 32(pad of 20) x K=128
      const int j = i - 57344, e = j & 7, l = (j >> 3) & 63, f = j >> 9;
      const int ot = f >> 2, kc = f & 3;
      const int m = ot * 16 + (l & 15);
      const int k = kc * 32 + ((l >> 4) << 3) + e;
      v = (m < 20) ? ow2[m * 128 + k] : 0.0f;
    }
    W[i] = f2bf(v);
  }
}

// ---------------- fused: one dopri5 step (6 fevals) + output head ------------
// 256 thr / 32 rows / 4 waves. Wave w: GEMM1 hidden cols [64w,64w+64),
// GEMM2 lat cols [16w,16w+16) full-K. Lane owns rows {li,16+li} x 4 contiguous
// lat cols latb..latb+3 (C-layout: n=lane&15=row, m=(lane>>4)*4+reg=col).
__global__ __launch_bounds__(256, 2) void fused_kernel(
    const float* __restrict__ zt, const float* __restrict__ ut,
    const u16* __restrict__ W,
    const float* __restrict__ ab1, const float* __restrict__ rb1,
    const float* __restrict__ ab2, const float* __restrict__ rb2,
    const float* __restrict__ ob1, const float* __restrict__ ob2,
    float* __restrict__ outz, float* __restrict__ outy)
{
  __shared__ __align__(16) u16 X2[32 * 320];   // [z(64)|H(256)] bf16, swizzled
  __shared__ __align__(16) u16 C1[32 * 256];   // u*W1u+b1 constant, bf16
  __shared__ __align__(16) u16 KS[4 * 32 * 64];// k1..k4 bf16, thread-private
  const int tid = threadIdx.x, w = tid >> 6, l = tid & 63, li = l & 15, h4 = l >> 4;
  const int R0 = blockIdx.x * 32;
  const int latb = w * 16 + 4 * h4;            // owned 4 lat cols
  const int r0 = li, r1 = 16 + li;             // owned rows

  // ---- persistent weight frags ----
  bf16x8 wg1[4][2];
  #pragma unroll
  for (int ct = 0; ct < 4; ++ct)
    #pragma unroll
    for (int kc = 0; kc < 2; ++kc)
      wg1[ct][kc] = *(const bf16x8*)(W + OFF_WG1 + (((w * 4 + ct) * 2 + kc) * 64 + l) * 8);
  bf16x8 wg2[10];
  #pragma unroll
  for (int kc = 0; kc < 10; ++kc)
    wg2[kc] = *(const bf16x8*)(W + OFF_WG2 + ((w * 10 + kc) * 64 + l) * 8);

  // ---- c2 = ab2+rb2 (f32, folded into GEMM2 acc init) ----
  f32x4 c24;
  #pragma unroll
  for (int r = 0; r < 4; ++r) c24[r] = ab2[latb + r] + rb2[latb + r];

  // ---- stage X2 z (full tile, thread-strided) ----
  {
    const int r = tid >> 3, c0 = (tid & 7) * 8;
    const float4 za = *(const float4*)&zt[(size_t)(R0 + r) * 64 + c0];
    const float4 zb = *(const float4*)&zt[(size_t)(R0 + r) * 64 + c0 + 4];
    *(uint4*)&X2[xi(r, c0)] =
        make_uint4(pk2(za.x, za.y), pk2(za.z, za.w), pk2(zb.x, zb.y), pk2(zb.z, zb.w));
  }
  // ---- z8 state (owned positions) ----
  float z8[8];
  {
    const float4 a = *(const float4*)&zt[(size_t)(R0 + r0) * 64 + latb];
    const float4 b = *(const float4*)&zt[(size_t)(R0 + r1) * 64 + latb];
    z8[0] = a.x; z8[1] = a.y; z8[2] = a.z; z8[3] = a.w;
    z8[4] = b.x; z8[5] = b.y; z8[6] = b.z; z8[7] = b.w;
  }
  // ---- C1 = u @ W1u^T + b1 (one MFMA pass, stored bf16) ----
  {
    bf16x8 uf[2];
    #pragma unroll
    for (int rt = 0; rt < 2; ++rt) {
      union { bf16x8 v; uint4 u; } t;
      if (h4 < 2) {
        const float4 ua = *(const float4*)&ut[(size_t)(R0 + rt * 16 + li) * 16 + h4 * 8];
        const float4 ub = *(const float4*)&ut[(size_t)(R0 + rt * 16 + li) * 16 + h4 * 8 + 4];
        t.u = make_uint4(pk2(ua.x, ua.y), pk2(ua.z, ua.w), pk2(ub.x, ub.y), pk2(ub.z, ub.w));
      } else t.u = make_uint4(0, 0, 0, 0);
      uf[rt] = t.v;
    }
    #pragma unroll
    for (int ct = 0; ct < 4; ++ct) {
      const bf16x8 w1u = *(const bf16x8*)(W + OFF_W1U + ((w * 4 + ct) * 64 + l) * 8);
      const int hcb = (w * 4 + ct) * 16 + 4 * h4;
      const float* bsrc = (hcb < 128) ? ab1 : rb1;
      const int boff = (hcb < 128) ? hcb : hcb - 128;
      f32x4 binit;
      #pragma unroll
      for (int r = 0; r < 4; ++r) binit[r] = bsrc[boff + r];
      #pragma unroll
      for (int rt = 0; rt < 2; ++rt) {
        f32x4 cc = __builtin_amdgcn_mfma_f32_16x16x32_bf16(w1u, uf[rt], binit, 0, 0, 0);
        *(uint2*)&C1[xiC(rt * 16 + li, hcb)] =
            make_uint2(pk2(cc[0], cc[1]), pk2(cc[2], cc[3]));
      }
    }
  }

  float kp8[8];

  auto feval = [&]() {
    __syncthreads();                          // zi (+C1 first time) visible
    // z-frags: used by GEMM1 AND GEMM2 (kc 0,1) -> held across sync
    bf16x8 bz[2][2];
    #pragma unroll
    for (int rt = 0; rt < 2; ++rt)
      #pragma unroll
      for (int kc = 0; kc < 2; ++kc)
        bz[rt][kc] = *(const bf16x8*)&X2[xi(rt * 16 + li, kc * 32 + h4 * 8)];
    // GEMM1: H = tanh(z@W1z + C1)
    #pragma unroll
    for (int ct = 0; ct < 4; ++ct) {
      const int hcb = (w * 4 + ct) * 16 + 4 * h4;
      #pragma unroll
      for (int rt = 0; rt < 2; ++rt) {
        const uint2 cc = *(const uint2*)&C1[xiC(rt * 16 + li, hcb)];
        f32x4 acc = {bfl(cc.x), bfh(cc.x), bfl(cc.y), bfh(cc.y)};
        acc = __builtin_amdgcn_mfma_f32_16x16x32_bf16(wg1[ct][0], bz[rt][0], acc, 0, 0, 0);
        acc = __builtin_amdgcn_mfma_f32_16x16x32_bf16(wg1[ct][1], bz[rt][1], acc, 0, 0, 0);
        const float t0 = tanhf_(acc[0]), t1 = tanhf_(acc[1]);
        const float t2 = tanhf_(acc[2]), t3 = tanhf_(acc[3]);
        *(uint2*)&X2[xi(rt * 16 + li, 64 + hcb)] = make_uint2(pk2(t0, t1), pk2(t2, t3));
      }
    }
    __syncthreads();                          // H visible; z reads done (in regs)
    // GEMM2: k = z@A^T + H@W2^T + c2   (K=320, kc 0,1 from bz regs)
    f32x4 acc2[2];
    acc2[0] = c24; acc2[1] = c24;
    #pragma unroll
    for (int rt = 0; rt < 2; ++rt) {
      acc2[rt] = __builtin_amdgcn_mfma_f32_16x16x32_bf16(wg2[0], bz[rt][0], acc2[rt], 0, 0, 0);
      acc2[rt] = __builtin_amdgcn_mfma_f32_16x16x32_bf16(wg2[1], bz[rt][1], acc2[rt], 0, 0, 0);
    }
    #pragma unroll
    for (int kc = 2; kc < 10; ++kc)
      #pragma unroll
      for (int rt = 0; rt < 2; ++rt) {
        const bf16x8 bh = *(const bf16x8*)&X2[xi(rt * 16 + li, kc * 32 + h4 * 8)];
        acc2[rt] = __builtin_amdgcn_mfma_f32_16x16x32_bf16(wg2[kc], bh, acc2[rt], 0, 0, 0);
      }
    #pragma unroll
    for (int rt = 0; rt < 2; ++rt)
      #pragma unroll
      for (int r = 0; r < 4; ++r) kp8[rt * 4 + r] = acc2[rt][r];
  };

  auto ksaddr = [&](int slot, int rt) -> int {
    const int r = rt * 16 + li;
    return (slot * 32 + r) * 64 + (latb ^ ((r & 7) << 2));
  };
  auto stks = [&](int slot) {
    #pragma unroll
    for (int rt = 0; rt < 2; ++rt)
      *(uint2*)&KS[ksaddr(slot, rt)] =
          make_uint2(pk2(kp8[rt * 4], kp8[rt * 4 + 1]), pk2(kp8[rt * 4 + 2], kp8[rt * 4 + 3]));
  };
  auto kadd = [&](int slot, float c, float* zi) {
    #pragma unroll
    for (int rt = 0; rt < 2; ++rt) {
      const uint2 v = *(const uint2*)&KS[ksaddr(slot, rt)];
      zi[rt * 4 + 0] += c * bfl(v.x); zi[rt * 4 + 1] += c * bfh(v.x);
      zi[rt * 4 + 2] += c * bfl(v.y); zi[rt * 4 + 3] += c * bfh(v.y);
    }
  };
  auto stzi = [&](const float* v) {
    #pragma unroll
    for (int rt = 0; rt < 2; ++rt)
      *(uint2*)&X2[xi(rt * 16 + li, latb)] =
          make_uint2(pk2(v[rt * 4], v[rt * 4 + 1]), pk2(v[rt * 4 + 2], v[rt * 4 + 3]));
  };

  float yac[8], zi[8];
  feval();                                     // k1
  #pragma unroll
  for (int i = 0; i < 8; ++i) { yac[i] = B50 * kp8[i]; zi[i] = z8[i] + A10 * kp8[i]; }
  stks(0); stzi(zi);
  feval();                                     // k2
  #pragma unroll
  for (int i = 0; i < 8; ++i) zi[i] = z8[i] + A21 * kp8[i];
  kadd(0, A20, zi); stks(1); stzi(zi);
  feval();                                     // k3
  #pragma unroll
  for (int i = 0; i < 8; ++i) { yac[i] += B52 * kp8[i]; zi[i] = z8[i] + A32 * kp8[i]; }
  kadd(0, A30, zi); kadd(1, A31, zi); stks(2); stzi(zi);
  feval();                                     // k4
  #pragma unroll
  for (int i = 0; i < 8; ++i) { yac[i] += B53 * kp8[i]; zi[i] = z8[i] + A43 * kp8[i]; }
  kadd(0, A40, zi); kadd(1, A41, zi); kadd(2, A42, zi); stks(3); stzi(zi);
  feval();                                     // k5
  #pragma unroll
  for (int i = 0; i < 8; ++i) { yac[i] += B54 * kp8[i]; zi[i] = z8[i] + A54 * kp8[i]; }
  kadd(0, A50, zi); kadd(1, A51, zi); kadd(2, A52, zi); kadd(3, A53, zi); stzi(zi);
  feval();                                     // k6
  #pragma unroll
  for (int i = 0; i < 8; ++i) z8[i] += yac[i] + B55 * kp8[i];
  stzi(z8);                                    // z_final -> X2 (bf16) for head
  // zt1 out (f32 from regs)
  *(float4*)&outz[(size_t)(R0 + r0) * 64 + latb] = make_float4(z8[0], z8[1], z8[2], z8[3]);
  *(float4*)&outz[(size_t)(R0 + r1) * 64 + latb] = make_float4(z8[4], z8[5], z8[6], z8[7]);

  // ---------------- output head ----------------
  __syncthreads();                             // z_final visible; k6 reads done
  // c1h = u @ Wh1u^T + ob1 (kept in regs)
  f32x4 c1h[2][2];
  {
    bf16x8 ufh[2];
    #pragma unroll
    for (int rt = 0; rt < 2; ++rt) {
      union { bf16x8 v; uint4 u; } t;
      if (h4 < 2) {
        const float4 ua = *(const float4*)&ut[(size_t)(R0 + rt * 16 + li) * 16 + h4 * 8];
        const float4 ub = *(const float4*)&ut[(size_t)(R0 + rt * 16 + li) * 16 + h4 * 8 + 4];
        t.u = make_uint4(pk2(ua.x, ua.y), pk2(ua.z, ua.w), pk2(ub.x, ub.y), pk2(ub.z, ub.w));
      } else t.u = make_uint4(0, 0, 0, 0);
      ufh[rt] = t.v;
    }
    #pragma unroll
    for (int j2 = 0; j2 < 2; ++j2) {
      const bf16x8 whu = *(const bf16x8*)(W + OFF_WH1U + ((w * 2 + j2) * 64 + l) * 8);
      const int hcb = (w * 2 + j2) * 16 + 4 * h4;
      f32x4 binit;
      #pragma unroll
      for (int r = 0; r < 4; ++r) binit[r] = ob1[hcb + r];
      #pragma unroll
      for (int rt = 0; rt < 2; ++rt)
        c1h[j2][rt] = __builtin_amdgcn_mfma_f32_16x16x32_bf16(whu, ufh[rt], binit, 0, 0, 0);
    }
  }
  // head GEMM1: relu(z@Wh1z + c1h) -> X2 H cols [0,128)
  {
    bf16x8 bzf[2][2];
    #pragma unroll
    for (int rt = 0; rt < 2; ++rt)
      #pragma unroll
      for (int kc = 0; kc < 2; ++kc)
        bzf[rt][kc] = *(const bf16x8*)&X2[xi(rt * 16 + li, kc * 32 + h4 * 8)];
    #pragma unroll
    for (int j2 = 0; j2 < 2; ++j2) {
      const bf16x8 wa = *(const bf16x8*)(W + OFF_WH1 + (((w * 2 + j2) * 2 + 0) * 64 + l) * 8);
      const bf16x8 wb = *(const bf16x8*)(W + OFF_WH1 + (((w * 2 + j2) * 2 + 1) * 64 + l) * 8);
      const int hcb = (w * 2 + j2) * 16 + 4 * h4;
      #pragma unroll
      for (int rt = 0; rt < 2; ++rt) {
        f32x4 acc = c1h[j2][rt];
        acc = __builtin_amdgcn_mfma_f32_16x16x32_bf16(wa, bzf[rt][0], acc, 0, 0, 0);
        acc = __builtin_amdgcn_mfma_f32_16x16x32_bf16(wb, bzf[rt][1], acc, 0, 0, 0);
        const float e0 = fmaxf(acc[0], 0.0f), e1 = fmaxf(acc[1], 0.0f);
        const float e2 = fmaxf(acc[2], 0.0f), e3 = fmaxf(acc[3], 0.0f);
        *(uint2*)&X2[xi(rt * 16 + li, 64 + hcb)] = make_uint2(pk2(e0, e1), pk2(e2, e3));
      }
    }
  }
  __syncthreads();
  // head GEMM2: waves 0,1 -> 20 output cols (pad 32)
  if (w < 2) {
    bf16x8 wh2[4];
    #pragma unroll
    for (int kc = 0; kc < 4; ++kc)
      wh2[kc] = *(const bf16x8*)(W + OFF_WH2 + ((w * 4 + kc) * 64 + l) * 8);
    const int ocb = w * 16 + 4 * h4;
    f32x4 acco[2];
    #pragma unroll
    for (int r = 0; r < 4; ++r) {
      const float bo = (ocb + r < 20) ? ob2[ocb + r] : 0.0f;
      acco[0][r] = bo; acco[1][r] = bo;
    }
    #pragma unroll
    for (int kc = 0; kc < 4; ++kc)
      #pragma unroll
      for (int rt = 0; rt < 2; ++rt) {
        const bf16x8 bh = *(const bf16x8*)&X2[xi(rt * 16 + li, 64 + kc * 32 + h4 * 8)];
        acco[rt] = __builtin_amdgcn_mfma_f32_16x16x32_bf16(wh2[kc], bh, acco[rt], 0, 0, 0);
      }
    if (ocb < 20) {
      *(float4*)&outy[(size_t)(R0 + r0) * 20 + ocb] =
          make_float4(acco[0][0], acco[0][1], acco[0][2], acco[0][3]);
      *(float4*)&outy[(size_t)(R0 + r1) * 20 + ocb] =
          make_float4(acco[1][0], acco[1][1], acco[1][2], acco[1][3]);
    }
  }
}

extern "C" void kernel_launch(void* const* d_in, const int* in_sizes, int n_in,
                              void* d_out, int out_size, void* d_ws, size_t ws_size,
                              hipStream_t stream) {
  const float* zt  = (const float*)d_in[0];
  const float* ut  = (const float*)d_in[2];
  const float* L   = (const float*)d_in[3];
  const float* aw1 = (const float*)d_in[4];
  const float* ab1 = (const float*)d_in[5];
  const float* aw2 = (const float*)d_in[6];
  const float* ab2 = (const float*)d_in[7];
  const float* rw1 = (const float*)d_in[8];
  const float* rb1 = (const float*)d_in[9];
  const float* rw2 = (const float*)d_in[10];
  const float* rb2 = (const float*)d_in[11];
  const float* ow1 = (const float*)d_in[12];
  const float* ob1 = (const float*)d_in[13];
  const float* ow2 = (const float*)d_in[14];
  const float* ob2 = (const float*)d_in[15];

  u16* W = (u16*)d_ws;
  float* outz = (float*)d_out;
  float* outy = outz + (size_t)131072 * 64;

  hipLaunchKernelGGL(setup_kernel, dim3(64), dim3(256), 0, stream,
      L, aw1, rw1, aw2, rw2, ow1, ow2, W);
  hipLaunchKernelGGL(fused_kernel, dim3(4096), dim3(256), 0, stream,
      zt, ut, W, ab1, rb1, ab2, rb2, ob1, ob2, outz, outy);
}

// Round 6
// 145.478 us; speedup vs baseline: 6.7268x; 1.2015x over previous
//
#include <hip/hip_runtime.h>

typedef unsigned short u16;
typedef unsigned int u32;
typedef __attribute__((ext_vector_type(8))) __bf16 bf16x8;
typedef __attribute__((ext_vector_type(4))) float f32x4;

#define F32(x) ((float)(x))
// dopri5, single fixed step h = 1 (B5[6]==0, no error estimate -> 6 stages)
constexpr float A10 = F32(1.0/5.0);
constexpr float A20 = F32(3.0/40.0),       A21 = F32(9.0/40.0);
constexpr float A30 = F32(44.0/45.0),      A31 = F32(-56.0/15.0),     A32 = F32(32.0/9.0);
constexpr float A40 = F32(19372.0/6561.0), A41 = F32(-25360.0/2187.0), A42 = F32(64448.0/6561.0), A43 = F32(-212.0/729.0);
constexpr float A50 = F32(9017.0/3168.0),  A51 = F32(-355.0/33.0),    A52 = F32(46732.0/5247.0), A53 = F32(49.0/176.0), A54 = F32(-5103.0/18656.0);
constexpr float B50 = F32(35.0/384.0), B52 = F32(500.0/1113.0), B53 = F32(125.0/192.0),
                B54 = F32(-2187.0/6784.0), B55 = F32(11.0/84.0);

// weight regions, u16 units
#define OFF_WG1   0        // [16 ct][2 kc]  GEMM1 z-part      (16384)
#define OFF_WG2   16384    // [4 ct][10 kc]  GEMM2 z|H         (20480)
#define OFF_W1U   36864    // [16 ct]        GEMM1 u-part pad32 (8192)
#define OFF_WH1   45056    // [8 ct][2 kc]   head L1 z-part     (8192)
#define OFF_WH1U  53248    // [8 ct]         head L1 u-part     (4096)
#define OFF_WH2   57344    // [2 ot][4 kc]   head L2            (4096)
#define W_TOTAL   61440

__device__ __forceinline__ u16 f2bf(float f) {
  __bf16 h = (__bf16)f;
  return __builtin_bit_cast(u16, h);
}
__device__ __forceinline__ u32 pk2(float a, float b) {
  return (u32)f2bf(a) | ((u32)f2bf(b) << 16);
}
__device__ __forceinline__ float bfl(u32 u) { return __builtin_bit_cast(float, u << 16); }
__device__ __forceinline__ float bfh(u32 u) { return __builtin_bit_cast(float, u & 0xffff0000u); }
__device__ __forceinline__ float tanhf_(float x) {
  // 1 - 2/(e^{2x}+1) with explicit fast rcp (avoids precise-div expansion)
  float e = __expf(2.0f * x);
  return 1.0f - 2.0f * __builtin_amdgcn_rcpf(e + 1.0f);
}
// X2 [32 r][320 c] bf16, granule-XOR swizzle
__device__ __forceinline__ int xi(int r, int c) {
  return r * 320 + (((c >> 3) ^ (r & 7)) << 3) + (c & 7);
}
// C1 [32 r][256 c]
__device__ __forceinline__ int xiC(int r, int c) {
  return r * 256 + (((c >> 3) ^ (r & 7)) << 3) + (c & 7);
}

// ---------------- setup: pack weights as 16x16x32 A-frags --------------------
// A-frag: lane l holds A[m = base + (l&15)][k = kc*32 + (l>>4)*8 + e]
__global__ void setup_kernel(const float* __restrict__ L,
  const float* __restrict__ aw1, const float* __restrict__ rw1,
  const float* __restrict__ aw2, const float* __restrict__ rw2,
  const float* __restrict__ ow1, const float* __restrict__ ow2,
  u16* __restrict__ W)
{
  const int gid = blockIdx.x * blockDim.x + threadIdx.x;
  const int gstr = gridDim.x * blockDim.x;
  for (int i = gid; i < W_TOTAL; i += gstr) {
    float v;
    if (i < 16384) {                 // Wg1: hidden 256 x K=64 (z)
      const int j = i, e = j & 7, l = (j >> 3) & 63, f = j >> 9;
      const int ct = f >> 1, kc = f & 1;
      const int m = ct * 16 + (l & 15);
      const int k = kc * 32 + ((l >> 4) << 3) + e;
      v = (m < 128) ? aw1[m * 80 + k] : rw1[(m - 128) * 80 + k];
    } else if (i < 36864) {          // Wg2: lat 64 x K=320 (z:A | H:w2)
      const int j = i - 16384, e = j & 7, l = (j >> 3) & 63, f = j >> 9;
      const int ct = f / 10, kc = f - ct * 10;
      const int m = ct * 16 + (l & 15);
      const int kk = kc * 32 + ((l >> 4) << 3) + e;
      if (kk < 64) {                 // A = -(L L^T)
        float s = 0.0f;
        for (int q = 0; q < 64; ++q) s += L[m * 64 + q] * L[kk * 64 + q];
        v = -s;
      } else if (kk < 192) v = aw2[m * 128 + (kk - 64)];
      else                 v = rw2[m * 128 + (kk - 192)];
    } else if (i < 45056) {          // W1u: hidden 256 x K=32 (u pad)
      const int j = i - 36864, e = j & 7, l = (j >> 3) & 63, ct = j >> 9;
      const int m = ct * 16 + (l & 15);
      const int k = ((l >> 4) << 3) + e;
      v = (k < 16) ? ((m < 128) ? aw1[m * 80 + 64 + k] : rw1[(m - 128) * 80 + 64 + k]) : 0.0f;
    } else if (i < 53248) {          // Wh1: head hidden 128 x K=64 (z)
      const int j = i - 45056, e = j & 7, l = (j >> 3) & 63, f = j >> 9;
      const int ct = f >> 1, kc = f & 1;
      const int m = ct * 16 + (l & 15);
      const int k = kc * 32 + ((l >> 4) << 3) + e;
      v = ow1[m * 80 + k];
    } else if (i < 57344) {          // Wh1u: head hidden 128 x K=32 (u pad)
      const int j = i - 53248, e = j & 7, l = (j >> 3) & 63, ct = j >> 9;
      const int m = ct * 16 + (l & 15);
      const int k = ((l >> 4) << 3) + e;
      v = (k < 16) ? ow1[m * 80 + 64 + k] : 0.0f;
    } else {                         // Wh2: out 32(pad of 20) x K=128
      const int j = i - 57344, e = j & 7, l = (j >> 3) & 63, f = j >> 9;
      const int ot = f >> 2, kc = f & 3;
      const int m = ot * 16 + (l & 15);
      const int k = kc * 32 + ((l >> 4) << 3) + e;
      v = (m < 20) ? ow2[m * 128 + k] : 0.0f;
    }
    W[i] = f2bf(v);
  }
}

// ---------------- fused: one dopri5 step (6 fevals) + output head ------------
// 256 thr / 32 rows / 4 waves. Wave w: GEMM1 hidden cols [64w,64w+64),
// GEMM2 lat cols [16w,16w+16) full-K. Lane owns rows {li,16+li} x 4 contiguous
// lat cols latb..latb+3 (C-layout: n=lane&15=row, m=(lane>>4)*4+reg=col).
__global__ __launch_bounds__(256, 3) void fused_kernel(
    const float* __restrict__ zt, const float* __restrict__ ut,
    const u16* __restrict__ W,
    const float* __restrict__ ab1, const float* __restrict__ rb1,
    const float* __restrict__ ab2, const float* __restrict__ rb2,
    const float* __restrict__ ob1, const float* __restrict__ ob2,
    float* __restrict__ outz, float* __restrict__ outy)
{
  __shared__ __align__(16) u16 X2[32 * 320];   // [z(64)|H(256)] bf16, swizzled
  __shared__ __align__(16) u16 C1[32 * 256];   // u*W1u+b1 constant, bf16
  __shared__ __align__(16) u16 KS[4 * 32 * 64];// k1..k4 bf16, thread-private
  const int tid = threadIdx.x, w = tid >> 6, l = tid & 63, li = l & 15, h4 = l >> 4;
  const int R0 = blockIdx.x * 32;
  const int latb = w * 16 + 4 * h4;            // owned 4 lat cols
  const int r0 = li, r1 = 16 + li;             // owned rows

  // ---- persistent weight frags ----
  bf16x8 wg1[4][2];
  #pragma unroll
  for (int ct = 0; ct < 4; ++ct)
    #pragma unroll
    for (int kc = 0; kc < 2; ++kc)
      wg1[ct][kc] = *(const bf16x8*)(W + OFF_WG1 + (((w * 4 + ct) * 2 + kc) * 64 + l) * 8);
  bf16x8 wg2[10];
  #pragma unroll
  for (int kc = 0; kc < 10; ++kc)
    wg2[kc] = *(const bf16x8*)(W + OFF_WG2 + ((w * 10 + kc) * 64 + l) * 8);

  // ---- c2 = ab2+rb2 (f32, folded into GEMM2 acc init) ----
  f32x4 c24;
  #pragma unroll
  for (int r = 0; r < 4; ++r) c24[r] = ab2[latb + r] + rb2[latb + r];

  // ---- stage X2 z (full tile, thread-strided) ----
  {
    const int r = tid >> 3, c0 = (tid & 7) * 8;
    const float4 za = *(const float4*)&zt[(size_t)(R0 + r) * 64 + c0];
    const float4 zb = *(const float4*)&zt[(size_t)(R0 + r) * 64 + c0 + 4];
    *(uint4*)&X2[xi(r, c0)] =
        make_uint4(pk2(za.x, za.y), pk2(za.z, za.w), pk2(zb.x, zb.y), pk2(zb.z, zb.w));
  }
  // ---- z8 state (owned positions) ----
  float z8[8];
  {
    const float4 a = *(const float4*)&zt[(size_t)(R0 + r0) * 64 + latb];
    const float4 b = *(const float4*)&zt[(size_t)(R0 + r1) * 64 + latb];
    z8[0] = a.x; z8[1] = a.y; z8[2] = a.z; z8[3] = a.w;
    z8[4] = b.x; z8[5] = b.y; z8[6] = b.z; z8[7] = b.w;
  }
  // ---- C1 = u @ W1u^T + b1 (one MFMA pass, stored bf16) ----
  {
    bf16x8 uf[2];
    #pragma unroll
    for (int rt = 0; rt < 2; ++rt) {
      union { bf16x8 v; uint4 u; } t;
      if (h4 < 2) {
        const float4 ua = *(const float4*)&ut[(size_t)(R0 + rt * 16 + li) * 16 + h4 * 8];
        const float4 ub = *(const float4*)&ut[(size_t)(R0 + rt * 16 + li) * 16 + h4 * 8 + 4];
        t.u = make_uint4(pk2(ua.x, ua.y), pk2(ua.z, ua.w), pk2(ub.x, ub.y), pk2(ub.z, ub.w));
      } else t.u = make_uint4(0, 0, 0, 0);
      uf[rt] = t.v;
    }
    #pragma unroll
    for (int ct = 0; ct < 4; ++ct) {
      const bf16x8 w1u = *(const bf16x8*)(W + OFF_W1U + ((w * 4 + ct) * 64 + l) * 8);
      const int hcb = (w * 4 + ct) * 16 + 4 * h4;
      const float* bsrc = (hcb < 128) ? ab1 : rb1;
      const int boff = (hcb < 128) ? hcb : hcb - 128;
      f32x4 binit;
      #pragma unroll
      for (int r = 0; r < 4; ++r) binit[r] = bsrc[boff + r];
      #pragma unroll
      for (int rt = 0; rt < 2; ++rt) {
        f32x4 cc = __builtin_amdgcn_mfma_f32_16x16x32_bf16(w1u, uf[rt], binit, 0, 0, 0);
        *(uint2*)&C1[xiC(rt * 16 + li, hcb)] =
            make_uint2(pk2(cc[0], cc[1]), pk2(cc[2], cc[3]));
      }
    }
  }

  float kp8[8];

  auto feval = [&]() {
    __syncthreads();                          // zi (+C1 first time) visible
    // z-frags: used by GEMM1 AND GEMM2 (kc 0,1) -> held across sync
    bf16x8 bz[2][2];
    #pragma unroll
    for (int rt = 0; rt < 2; ++rt)
      #pragma unroll
      for (int kc = 0; kc < 2; ++kc)
        bz[rt][kc] = *(const bf16x8*)&X2[xi(rt * 16 + li, kc * 32 + h4 * 8)];
    // GEMM1: H = tanh(z@W1z + C1)
    #pragma unroll
    for (int ct = 0; ct < 4; ++ct) {
      const int hcb = (w * 4 + ct) * 16 + 4 * h4;
      #pragma unroll
      for (int rt = 0; rt < 2; ++rt) {
        const uint2 cc = *(const uint2*)&C1[xiC(rt * 16 + li, hcb)];
        f32x4 acc = {bfl(cc.x), bfh(cc.x), bfl(cc.y), bfh(cc.y)};
        acc = __builtin_amdgcn_mfma_f32_16x16x32_bf16(wg1[ct][0], bz[rt][0], acc, 0, 0, 0);
        acc = __builtin_amdgcn_mfma_f32_16x16x32_bf16(wg1[ct][1], bz[rt][1], acc, 0, 0, 0);
        const float t0 = tanhf_(acc[0]), t1 = tanhf_(acc[1]);
        const float t2 = tanhf_(acc[2]), t3 = tanhf_(acc[3]);
        *(uint2*)&X2[xi(rt * 16 + li, 64 + hcb)] = make_uint2(pk2(t0, t1), pk2(t2, t3));
      }
    }
    __syncthreads();                          // H visible; z reads done (in regs)
    // GEMM2: k = z@A^T + H@W2^T + c2   (K=320, kc 0,1 from bz regs)
    f32x4 acc2[2];
    acc2[0] = c24; acc2[1] = c24;
    #pragma unroll
    for (int rt = 0; rt < 2; ++rt) {
      acc2[rt] = __builtin_amdgcn_mfma_f32_16x16x32_bf16(wg2[0], bz[rt][0], acc2[rt], 0, 0, 0);
      acc2[rt] = __builtin_amdgcn_mfma_f32_16x16x32_bf16(wg2[1], bz[rt][1], acc2[rt], 0, 0, 0);
    }
    #pragma unroll
    for (int kc = 2; kc < 10; ++kc)
      #pragma unroll
      for (int rt = 0; rt < 2; ++rt) {
        const bf16x8 bh = *(const bf16x8*)&X2[xi(rt * 16 + li, kc * 32 + h4 * 8)];
        acc2[rt] = __builtin_amdgcn_mfma_f32_16x16x32_bf16(wg2[kc], bh, acc2[rt], 0, 0, 0);
      }
    #pragma unroll
    for (int rt = 0; rt < 2; ++rt)
      #pragma unroll
      for (int r = 0; r < 4; ++r) kp8[rt * 4 + r] = acc2[rt][r];
  };

  auto ksaddr = [&](int slot, int rt) -> int {
    const int r = rt * 16 + li;
    return (slot * 32 + r) * 64 + (latb ^ ((r & 7) << 2));
  };
  auto stks = [&](int slot) {
    #pragma unroll
    for (int rt = 0; rt < 2; ++rt)
      *(uint2*)&KS[ksaddr(slot, rt)] =
          make_uint2(pk2(kp8[rt * 4], kp8[rt * 4 + 1]), pk2(kp8[rt * 4 + 2], kp8[rt * 4 + 3]));
  };
  auto kadd = [&](int slot, float c, float* zi) {
    #pragma unroll
    for (int rt = 0; rt < 2; ++rt) {
      const uint2 v = *(const uint2*)&KS[ksaddr(slot, rt)];
      zi[rt * 4 + 0] += c * bfl(v.x); zi[rt * 4 + 1] += c * bfh(v.x);
      zi[rt * 4 + 2] += c * bfl(v.y); zi[rt * 4 + 3] += c * bfh(v.y);
    }
  };
  auto stzi = [&](const float* v) {
    #pragma unroll
    for (int rt = 0; rt < 2; ++rt)
      *(uint2*)&X2[xi(rt * 16 + li, latb)] =
          make_uint2(pk2(v[rt * 4], v[rt * 4 + 1]), pk2(v[rt * 4 + 2], v[rt * 4 + 3]));
  };

  float yac[8], zi[8];
  feval();                                     // k1
  #pragma unroll
  for (int i = 0; i < 8; ++i) { yac[i] = B50 * kp8[i]; zi[i] = z8[i] + A10 * kp8[i]; }
  stks(0); stzi(zi);
  feval();                                     // k2
  #pragma unroll
  for (int i = 0; i < 8; ++i) zi[i] = z8[i] + A21 * kp8[i];
  kadd(0, A20, zi); stks(1); stzi(zi);
  feval();                                     // k3
  #pragma unroll
  for (int i = 0; i < 8; ++i) { yac[i] += B52 * kp8[i]; zi[i] = z8[i] + A32 * kp8[i]; }
  kadd(0, A30, zi); kadd(1, A31, zi); stks(2); stzi(zi);
  feval();                                     // k4
  #pragma unroll
  for (int i = 0; i < 8; ++i) { yac[i] += B53 * kp8[i]; zi[i] = z8[i] + A43 * kp8[i]; }
  kadd(0, A40, zi); kadd(1, A41, zi); kadd(2, A42, zi); stks(3); stzi(zi);
  feval();                                     // k5
  #pragma unroll
  for (int i = 0; i < 8; ++i) { yac[i] += B54 * kp8[i]; zi[i] = z8[i] + A54 * kp8[i]; }
  kadd(0, A50, zi); kadd(1, A51, zi); kadd(2, A52, zi); kadd(3, A53, zi); stzi(zi);
  feval();                                     // k6
  #pragma unroll
  for (int i = 0; i < 8; ++i) z8[i] += yac[i] + B55 * kp8[i];
  stzi(z8);                                    // z_final -> X2 (bf16) for head
  // zt1 out (f32 from regs)
  *(float4*)&outz[(size_t)(R0 + r0) * 64 + latb] = make_float4(z8[0], z8[1], z8[2], z8[3]);
  *(float4*)&outz[(size_t)(R0 + r1) * 64 + latb] = make_float4(z8[4], z8[5], z8[6], z8[7]);

  // ---------------- output head ----------------
  __syncthreads();                             // z_final visible; k6 reads done
  // c1h = u @ Wh1u^T + ob1 (kept in regs)
  f32x4 c1h[2][2];
  {
    bf16x8 ufh[2];
    #pragma unroll
    for (int rt = 0; rt < 2; ++rt) {
      union { bf16x8 v; uint4 u; } t;
      if (h4 < 2) {
        const float4 ua = *(const float4*)&ut[(size_t)(R0 + rt * 16 + li) * 16 + h4 * 8];
        const float4 ub = *(const float4*)&ut[(size_t)(R0 + rt * 16 + li) * 16 + h4 * 8 + 4];
        t.u = make_uint4(pk2(ua.x, ua.y), pk2(ua.z, ua.w), pk2(ub.x, ub.y), pk2(ub.z, ub.w));
      } else t.u = make_uint4(0, 0, 0, 0);
      ufh[rt] = t.v;
    }
    #pragma unroll
    for (int j2 = 0; j2 < 2; ++j2) {
      const bf16x8 whu = *(const bf16x8*)(W + OFF_WH1U + ((w * 2 + j2) * 64 + l) * 8);
      const int hcb = (w * 2 + j2) * 16 + 4 * h4;
      f32x4 binit;
      #pragma unroll
      for (int r = 0; r < 4; ++r) binit[r] = ob1[hcb + r];
      #pragma unroll
      for (int rt = 0; rt < 2; ++rt)
        c1h[j2][rt] = __builtin_amdgcn_mfma_f32_16x16x32_bf16(whu, ufh[rt], binit, 0, 0, 0);
    }
  }
  // head GEMM1: relu(z@Wh1z + c1h) -> X2 H cols [0,128)
  {
    bf16x8 bzf[2][2];
    #pragma unroll
    for (int rt = 0; rt < 2; ++rt)
      #pragma unroll
      for (int kc = 0; kc < 2; ++kc)
        bzf[rt][kc] = *(const bf16x8*)&X2[xi(rt * 16 + li, kc * 32 + h4 * 8)];
    #pragma unroll
    for (int j2 = 0; j2 < 2; ++j2) {
      const bf16x8 wa = *(const bf16x8*)(W + OFF_WH1 + (((w * 2 + j2) * 2 + 0) * 64 + l) * 8);
      const bf16x8 wb = *(const bf16x8*)(W + OFF_WH1 + (((w * 2 + j2) * 2 + 1) * 64 + l) * 8);
      const int hcb = (w * 2 + j2) * 16 + 4 * h4;
      #pragma unroll
      for (int rt = 0; rt < 2; ++rt) {
        f32x4 acc = c1h[j2][rt];
        acc = __builtin_amdgcn_mfma_f32_16x16x32_bf16(wa, bzf[rt][0], acc, 0, 0, 0);
        acc = __builtin_amdgcn_mfma_f32_16x16x32_bf16(wb, bzf[rt][1], acc, 0, 0, 0);
        const float e0 = fmaxf(acc[0], 0.0f), e1 = fmaxf(acc[1], 0.0f);
        const float e2 = fmaxf(acc[2], 0.0f), e3 = fmaxf(acc[3], 0.0f);
        *(uint2*)&X2[xi(rt * 16 + li, 64 + hcb)] = make_uint2(pk2(e0, e1), pk2(e2, e3));
      }
    }
  }
  __syncthreads();
  // head GEMM2: waves 0,1 -> 20 output cols (pad 32)
  if (w < 2) {
    bf16x8 wh2[4];
    #pragma unroll
    for (int kc = 0; kc < 4; ++kc)
      wh2[kc] = *(const bf16x8*)(W + OFF_WH2 + ((w * 4 + kc) * 64 + l) * 8);
    const int ocb = w * 16 + 4 * h4;
    f32x4 acco[2];
    #pragma unroll
    for (int r = 0; r < 4; ++r) {
      const float bo = (ocb + r < 20) ? ob2[ocb + r] : 0.0f;
      acco[0][r] = bo; acco[1][r] = bo;
    }
    #pragma unroll
    for (int kc = 0; kc < 4; ++kc)
      #pragma unroll
      for (int rt = 0; rt < 2; ++rt) {
        const bf16x8 bh = *(const bf16x8*)&X2[xi(rt * 16 + li, 64 + kc * 32 + h4 * 8)];
        acco[rt] = __builtin_amdgcn_mfma_f32_16x16x32_bf16(wh2[kc], bh, acco[rt], 0, 0, 0);
      }
    if (ocb < 20) {
      *(float4*)&outy[(size_t)(R0 + r0) * 20 + ocb] =
          make_float4(acco[0][0], acco[0][1], acco[0][2], acco[0][3]);
      *(float4*)&outy[(size_t)(R0 + r1) * 20 + ocb] =
          make_float4(acco[1][0], acco[1][1], acco[1][2], acco[1][3]);
    }
  }
}

extern "C" void kernel_launch(void* const* d_in, const int* in_sizes, int n_in,
                              void* d_out, int out_size, void* d_ws, size_t ws_size,
                              hipStream_t stream) {
  const float* zt  = (const float*)d_in[0];
  const float* ut  = (const float*)d_in[2];
  const float* L   = (const float*)d_in[3];
  const float* aw1 = (const float*)d_in[4];
  const float* ab1 = (const float*)d_in[5];
  const float* aw2 = (const float*)d_in[6];
  const float* ab2 = (const float*)d_in[7];
  const float* rw1 = (const float*)d_in[8];
  const float* rb1 = (const float*)d_in[9];
  const float* rw2 = (const float*)d_in[10];
  const float* rb2 = (const float*)d_in[11];
  const float* ow1 = (const float*)d_in[12];
  const float* ob1 = (const float*)d_in[13];
  const float* ow2 = (const float*)d_in[14];
  const float* ob2 = (const float*)d_in[15];

  u16* W = (u16*)d_ws;
  float* outz = (float*)d_out;
  float* outy = outz + (size_t)131072 * 64;

  hipLaunchKernelGGL(setup_kernel, dim3(64), dim3(256), 0, stream,
      L, aw1, rw1, aw2, rw2, ow1, ow2, W);
  hipLaunchKernelGGL(fused_kernel, dim3(4096), dim3(256), 0, stream,
      zt, ut, W, ab1, rb1, ab2, rb2, ob1, ob2, outz, outy);
}